// Round 5
// baseline (403.908 us; speedup 1.0000x reference)
//
#include <hip/hip_runtime.h>
#include <cstdint>
#include <cstddef>

typedef __bf16 bf16;
typedef __bf16 bf16x4 __attribute__((ext_vector_type(4)));
typedef __bf16 bf16x8 __attribute__((ext_vector_type(8)));
typedef float  f32x4  __attribute__((ext_vector_type(4)));
typedef short  s16x4  __attribute__((ext_vector_type(4)));

#define HIDDEN 2048
#define NHEADS 16
#define HDIM   128
#define BSZ    2
#define SEQ    2048
#define BS     (BSZ*SEQ)     /* 4096 rows */
#define QKW    (2*HIDDEN)    /* 4096: Q|K concat width */

union b4u { bf16x4 h; s16x4 s; };

// async global->LDS, 16B per lane. LDS dest = wave-uniform base + lane*16.
__device__ __forceinline__ void async16(const bf16* g, bf16* l) {
    __builtin_amdgcn_global_load_lds(
        (const __attribute__((address_space(1))) unsigned int*)g,
        (__attribute__((address_space(3))) unsigned int*)l, 16, 0, 0);
}

// ---------------------------------------------------------------- fused casts + rope table
__global__ __launch_bounds__(256) void cast_all(const float* __restrict__ hs,
                                                const float* __restrict__ Wq,
                                                const float* __restrict__ Wk,
                                                const float* __restrict__ Wv,
                                                const float* __restrict__ Wo,
                                                const int* __restrict__ pos,
                                                bf16* __restrict__ hs_b,
                                                bf16* __restrict__ wqkv,
                                                bf16* __restrict__ wo_b,
                                                float2* __restrict__ tab) {
    int i = blockIdx.x * 256 + threadIdx.x;
    if (i >= 6291456) {                       // rope table region
        int j = i - 6291456;                  // 0..131071
        int s = j >> 6, p = j & 63;
        float t = (float)pos[s];
        float inv = expf(-(float)(2 * p) * (9.2103403719761836f / 128.0f));
        float sn, cs;
        sincosf(t * inv, &sn, &cs);
        tab[j] = make_float2(cs, sn);
        return;
    }
    const float* src; bf16* dst; int off;
    if (i < 2097152) { src = hs; dst = hs_b; off = i; }
    else {
        int j = i - 2097152;
        int r = j >> 20;
        off = j & 1048575;
        if      (r == 0) { src = Wq; dst = wqkv; }
        else if (r == 1) { src = Wk; dst = wqkv + (size_t)4194304; }
        else if (r == 2) { src = Wv; dst = wqkv + (size_t)8388608; }
        else             { src = Wo; dst = wo_b; }
    }
    const float4 v = ((const float4*)src)[off];
    bf16x4 o;
    o.x = (bf16)v.x; o.y = (bf16)v.y; o.z = (bf16)v.z; o.w = (bf16)v.w;
    ((bf16x4*)dst)[off] = o;
}

// ================================================================ BK=64 GEMM core
// LDS tile layout: [128 rows][64 el], 8 chunks of 16B per row, chunk c of row r
// stored at physical c^(r&7). Staging: wave w covers rows w*32..w*32+31 with 4
// async16; lane l -> row w*32+i*8+(l>>3), fetches logical chunk (l&7)^(l>>3).

// ---------------------------------------------------------------- fused QKV GEMM + RoPE + V^T
__global__ __launch_bounds__(256) void gemm_qkv(const bf16* __restrict__ A,
                                                const bf16* __restrict__ Bt,
                                                const float2* __restrict__ tab,
                                                bf16* __restrict__ qk,
                                                bf16* __restrict__ vtb) {
    __shared__ bf16 Als[128 * 64];
    __shared__ bf16 Bls[128 * 64];
    const int K    = HIDDEN;
    const int tid  = threadIdx.x;
    const int lane = tid & 63;
    const int w    = tid >> 6;
    const int l15  = lane & 15;
    const int quad = lane >> 4;
    const int sw   = l15 & 7;
    const int mTile = blockIdx.y * 128;
    const int nTile = blockIdx.x * 128;
    const int wm = (w >> 1) * 64;
    const int wv = w & 1;

    f32x4 acc[4][4];
#pragma unroll
    for (int i = 0; i < 4; ++i)
#pragma unroll
        for (int j = 0; j < 4; ++j) acc[i][j] = (f32x4){0.f, 0.f, 0.f, 0.f};

    const int cOff = (((lane & 7) ^ (lane >> 3)) & 7) * 8;
    const bf16* gA = A + (size_t)(mTile + w * 32 + (lane >> 3)) * K + cOff;
    const bf16* gB = Bt + (size_t)(nTile + w * 32 + (lane >> 3)) * K + cOff;
    bf16* lA = Als + w * 2048;
    bf16* lB = Bls + w * 2048;
    const int rstep = 8 * K;

    for (int k0 = 0; k0 < K; k0 += 64) {
#pragma unroll
        for (int i = 0; i < 4; ++i) async16(gA + k0 + i * rstep, lA + i * 512);
#pragma unroll
        for (int i = 0; i < 4; ++i) async16(gB + k0 + i * rstep, lB + i * 512);
        __syncthreads();

#pragma unroll
        for (int s = 0; s < 2; ++s) {
            bf16x8 af[4], bfr[4];
#pragma unroll
            for (int mi = 0; mi < 4; ++mi)
                af[mi] = *(const bf16x8*)(Als + (wm + mi * 16 + l15) * 64 +
                                          (((s * 4 + quad) ^ sw) << 3));
#pragma unroll
            for (int ni = 0; ni < 4; ++ni) {
                int co = wv * 32 + (ni & 1) * 16 + (ni >> 1) * 64;
                bfr[ni] = *(const bf16x8*)(Bls + (co + l15) * 64 +
                                           (((s * 4 + quad) ^ sw) << 3));
            }
#pragma unroll
            for (int mi = 0; mi < 4; ++mi)
#pragma unroll
                for (int ni = 0; ni < 4; ++ni)
                    acc[mi][ni] = __builtin_amdgcn_mfma_f32_16x16x32_bf16(
                        af[mi], bfr[ni], acc[mi][ni], 0, 0, 0);
        }
        __syncthreads();
    }

    if (nTile < QKW) {
        // RoPE epilogue: acc[ni] (d<64 half) pairs with acc[ni+2] (d>=64 half), same lane
#pragma unroll
        for (int mi = 0; mi < 4; ++mi)
#pragma unroll
            for (int r = 0; r < 4; ++r) {
                int row = mTile + wm + mi * 16 + quad * 4 + r;
                int s   = row & (SEQ - 1);
                float2 t0 = tab[s * 64 + wv * 32 + l15];
                float2 t1 = tab[s * 64 + wv * 32 + 16 + l15];
                size_t rb = (size_t)row * QKW + nTile + wv * 32 + l15;
                float lo0 = acc[mi][0][r], hi0 = acc[mi][2][r];
                float lo1 = acc[mi][1][r], hi1 = acc[mi][3][r];
                qk[rb]      = (bf16)(lo0 * t0.x - hi0 * t0.y);
                qk[rb + 64] = (bf16)(hi0 * t0.x + lo0 * t0.y);
                qk[rb + 16] = (bf16)(lo1 * t1.x - hi1 * t1.y);
                qk[rb + 80] = (bf16)(hi1 * t1.x + lo1 * t1.y);
            }
    } else {
        // V region: store transposed, vt[feature][token], 8B column segments
#pragma unroll
        for (int mi = 0; mi < 4; ++mi)
#pragma unroll
            for (int ni = 0; ni < 4; ++ni) {
                int col_v = (nTile - QKW) + wv * 32 + (ni & 1) * 16 + (ni >> 1) * 64 + l15;
                int row0  = mTile + wm + mi * 16 + quad * 4;
                bf16x4 pk;
#pragma unroll
                for (int r = 0; r < 4; ++r) pk[r] = (bf16)acc[mi][ni][r];
                *(bf16x4*)(vtb + (size_t)col_v * BS + row0) = pk;
            }
    }
}

// ---------------------------------------------------------------- GEMM: C = A * Bt^T (final proj), BK=64
template <typename OutT>
__global__ __launch_bounds__(256) void gemm_bt(const bf16* __restrict__ A,
                                               const bf16* __restrict__ Bt,
                                               OutT* __restrict__ C,
                                               int M, int N, int K) {
    __shared__ bf16 Als[128 * 64];
    __shared__ bf16 Bls[128 * 64];
    const int tid  = threadIdx.x;
    const int lane = tid & 63;
    const int w    = tid >> 6;
    const int l15  = lane & 15;
    const int quad = lane >> 4;
    const int sw   = l15 & 7;
    const int mTile = blockIdx.y * 128;
    const int nTile = blockIdx.x * 128;
    const int wm = (w >> 1) * 64;
    const int wn = (w & 1) * 64;

    f32x4 acc[4][4];
#pragma unroll
    for (int i = 0; i < 4; ++i)
#pragma unroll
        for (int j = 0; j < 4; ++j) acc[i][j] = (f32x4){0.f, 0.f, 0.f, 0.f};

    const int cOff = (((lane & 7) ^ (lane >> 3)) & 7) * 8;
    const bf16* gA = A + (size_t)(mTile + w * 32 + (lane >> 3)) * K + cOff;
    const bf16* gB = Bt + (size_t)(nTile + w * 32 + (lane >> 3)) * K + cOff;
    bf16* lA = Als + w * 2048;
    bf16* lB = Bls + w * 2048;
    const int rstep = 8 * K;

    for (int k0 = 0; k0 < K; k0 += 64) {
#pragma unroll
        for (int i = 0; i < 4; ++i) async16(gA + k0 + i * rstep, lA + i * 512);
#pragma unroll
        for (int i = 0; i < 4; ++i) async16(gB + k0 + i * rstep, lB + i * 512);
        __syncthreads();

#pragma unroll
        for (int s = 0; s < 2; ++s) {
            bf16x8 af[4], bfr[4];
#pragma unroll
            for (int mi = 0; mi < 4; ++mi)
                af[mi] = *(const bf16x8*)(Als + (wm + mi * 16 + l15) * 64 +
                                          (((s * 4 + quad) ^ sw) << 3));
#pragma unroll
            for (int ni = 0; ni < 4; ++ni)
                bfr[ni] = *(const bf16x8*)(Bls + (wn + ni * 16 + l15) * 64 +
                                           (((s * 4 + quad) ^ sw) << 3));
#pragma unroll
            for (int mi = 0; mi < 4; ++mi)
#pragma unroll
                for (int ni = 0; ni < 4; ++ni)
                    acc[mi][ni] = __builtin_amdgcn_mfma_f32_16x16x32_bf16(
                        af[mi], bfr[ni], acc[mi][ni], 0, 0, 0);
        }
        __syncthreads();
    }

#pragma unroll
    for (int mi = 0; mi < 4; ++mi)
#pragma unroll
        for (int ni = 0; ni < 4; ++ni)
#pragma unroll
            for (int r = 0; r < 4; ++r) {
                int row = mTile + wm + mi * 16 + quad * 4 + r;
                int col = nTile + wn + ni * 16 + l15;
                C[(size_t)row * N + col] = (OutT)acc[mi][ni][r];
            }
}

// ---------------------------------------------------------------- flash attention (S^T form, 128 q-rows/block)
// qk: [4096][4096] rows=token, cols [0,2048)=Q, [2048,4096)=K (RoPE'd)
// vt: [2048][4096] rows=feature (h*128+d), cols=token
// grid 512 = (b,h) x 16 q-tiles of 128 rows; 8 waves, wave w owns rows [qbase+16w,+16).
// S^T = K·Q^T; lane-scalar softmax; P^T -> 16x16x16 MFMA B-operand (no LDS roundtrip).
// Waves fully above the diagonal skip compute (staging+barriers only).
__global__ __launch_bounds__(512) void attn_kernel(const bf16* __restrict__ qk,
                                                   const bf16* __restrict__ vt,
                                                   bf16* __restrict__ ao) {
    __shared__ bf16 Kls[64 * 128];   // [j][d], 16 chunks/row: phys (c&8)|((c&7)^(j&7))
    __shared__ bf16 Vls[128 * 64];   // [d][s], 8 chunks/row: phys c^(d&7)

    const int tid  = threadIdx.x;
    const int lane = tid & 63;
    const int w    = tid >> 6;       // 0..7
    const int l15  = lane & 15;
    const int quad = lane >> 4;
    const int bid  = blockIdx.x;
    const int qt   = 15 - (bid >> 5);   // longest blocks dispatch first
    const int bh   = bid & 31;
    const int b    = bh >> 4;
    const int h    = bh & 15;
    const int qbase = qt * 128;
    const size_t seq0 = (size_t)b * SEQ;

    // Q fragments (B-operand: n=l15=q-row, k=quad*8+j)
    bf16x8 qf[4];
    {
        const bf16* qp = qk + (seq0 + qbase + w * 16 + l15) * QKW + h * HDIM + quad * 8;
#pragma unroll
        for (int ks = 0; ks < 4; ++ks) qf[ks] = *(const bf16x8*)(qp + ks * 32);
    }

    f32x4 o[8];   // O^T: q-row = l15, d = n2*16 + quad*4 + r
#pragma unroll
    for (int i = 0; i < 8; ++i) o[i] = (f32x4){0.f, 0.f, 0.f, 0.f};
    float m_s = -3e38f, l_s = 0.f;
    const int qg = qbase + w * 16 + l15;     // this lane's q-row (global)
    const int wmin = qbase + w * 16;         // wave's lowest q-row

    // K staging (2 insts/wave): lane -> row j=(w*2+i)*4+(l>>4), phys chunk kp=l&15
    const int kp   = lane & 15;
    const int sw   = l15 & 7;
    const int tmax = 2 * qt + 1;

    for (int t = 0; t <= tmax; ++t) {
        const int kb = t * 64;
#pragma unroll
        for (int i = 0; i < 2; ++i) {
            int j = (w * 2 + i) * 4 + (lane >> 4);
            int c = (kp & 8) | ((kp & 7) ^ (j & 7));
            async16(qk + (seq0 + kb + j) * QKW + HIDDEN + h * HDIM + c * 8,
                    Kls + (w * 2 + i) * 512);
        }
#pragma unroll
        for (int i = 0; i < 2; ++i) {
            int d = (w * 2 + i) * 8 + (lane >> 3);
            int c = (lane & 7) ^ (d & 7);
            async16(vt + (size_t)(h * HDIM + d) * (size_t)BS + seq0 + kb + c * 8,
                    Vls + (w * 2 + i) * 512);
        }
        __syncthreads();

        if (kb <= wmin + 15) {       // wave has at least one unmasked key
            // S^T = K Q^T: sa[ni] col=l15 (q-row), row=quad*4+r (key ni*16+..)
            f32x4 sa[4];
#pragma unroll
            for (int ni = 0; ni < 4; ++ni) sa[ni] = (f32x4){0.f, 0.f, 0.f, 0.f};
#pragma unroll
            for (int ni = 0; ni < 4; ++ni)
#pragma unroll
                for (int ks = 0; ks < 4; ++ks) {
                    bf16x8 kf = *(const bf16x8*)(Kls + (ni * 16 + l15) * 128 +
                                                 (((ks * 4 + quad) ^ sw) << 3));
                    sa[ni] = __builtin_amdgcn_mfma_f32_16x16x32_bf16(kf, qf[ks], sa[ni], 0, 0, 0);
                }

            const float scale = 0.08838834764831845f * 1.4426950408889634f;
            float rmax = -3e38f;
            const bool diag = (kb + 63 > wmin);
#pragma unroll
            for (int ni = 0; ni < 4; ++ni)
#pragma unroll
                for (int r = 0; r < 4; ++r) {
                    float sv = sa[ni][r] * scale;
                    if (diag) {
                        int jg = kb + ni * 16 + quad * 4 + r;
                        if (jg > qg) sv = -1e30f;
                    }
                    sa[ni][r] = sv;
                    rmax = fmaxf(rmax, sv);
                }
            rmax = fmaxf(rmax, __shfl_xor(rmax, 16));
            rmax = fmaxf(rmax, __shfl_xor(rmax, 32));

            float mn = fmaxf(m_s, rmax);
            float alpha = exp2f(m_s - mn);
            m_s = mn;
            float rsum = 0.f;
            b4u pb[4];
#pragma unroll
            for (int ni = 0; ni < 4; ++ni)
#pragma unroll
                for (int r = 0; r < 4; ++r) {
                    float e = exp2f(sa[ni][r] - mn);
                    rsum += e;
                    pb[ni].h[r] = (bf16)e;
                }
            rsum += __shfl_xor(rsum, 16);
            rsum += __shfl_xor(rsum, 32);
            l_s = l_s * alpha + rsum;

            if (__ballot(alpha != 1.f) != 0ull) {
#pragma unroll
                for (int n2 = 0; n2 < 8; ++n2)
#pragma unroll
                    for (int r = 0; r < 4; ++r) o[n2][r] *= alpha;
            }

            // O^T += V^T P^T : A = V^T frag (m=l15=d, k=quad*4+i=j), B = pb[ni]
#pragma unroll
            for (int n2 = 0; n2 < 8; ++n2)
#pragma unroll
                for (int ni = 0; ni < 4; ++ni) {
                    b4u vf;
                    vf.h = *(const bf16x4*)(Vls + (n2 * 16 + l15) * 64 +
                                            ((((ni * 2 + (quad >> 1)) ^ sw) << 3) + (quad & 1) * 4));
                    o[n2] = __builtin_amdgcn_mfma_f32_16x16x16bf16_1k(vf.s, pb[ni].s, o[n2], 0, 0, 0);
                }
        }
        __syncthreads();
    }

    const float inv = 1.0f / l_s;
    bf16* op = ao + (seq0 + qg) * HIDDEN + h * HDIM + quad * 4;
#pragma unroll
    for (int n2 = 0; n2 < 8; ++n2) {
        bf16x4 pk;
#pragma unroll
        for (int r = 0; r < 4; ++r) pk[r] = (bf16)(o[n2][r] * inv);
        *(bf16x4*)(op + n2 * 16) = pk;
    }
}

// ---------------------------------------------------------------- launch
extern "C" void kernel_launch(void* const* d_in, const int* in_sizes, int n_in,
                              void* d_out, int out_size, void* d_ws, size_t ws_size,
                              hipStream_t stream) {
    const float* hs = (const float*)d_in[0];
    const float* Wq = (const float*)d_in[1];
    const float* Wk = (const float*)d_in[2];
    const float* Wv = (const float*)d_in[3];
    const float* Wo = (const float*)d_in[4];
    const int* pos  = (const int*)d_in[6];
    float* out = (float*)d_out;

    bf16* hs_b = (bf16*)d_ws;                               //  8,388,608 el
    bf16* wqkv = hs_b + (size_t)8388608;                    // 12,582,912 el [6144][2048]
    bf16* wo_b = wqkv + (size_t)12582912;                   //  4,194,304 el
    bf16* qkb  = wo_b + (size_t)4194304;                    // 16,777,216 el [4096][4096]
    bf16* vtb  = qkb + (size_t)16777216;                    //  8,388,608 el [2048][4096]
    bf16* ao   = vtb + (size_t)8388608;                     //  8,388,608 el
    float2* tab = (float2*)ao;  // 1 MB, consumed by gemm_qkv BEFORE attn writes ao
    // total: 117,440,512 B

    cast_all<<<25088, 256, 0, stream>>>(hs, Wq, Wk, Wv, Wo, pos, hs_b, wqkv, wo_b, tab);
    gemm_qkv<<<dim3(48, 32), 256, 0, stream>>>(hs_b, wqkv, tab, qkb, vtb);
    attn_kernel<<<512, 512, 0, stream>>>(qkb, vtb, ao);
    gemm_bt<float><<<dim3(HIDDEN / 128, BS / 128), 256, 0, stream>>>(ao, wo_b, out, BS, HIDDEN, HIDDEN);
}